// Round 10
// baseline (599.747 us; speedup 1.0000x reference)
//
#include <hip/hip_runtime.h>
#include <math.h>

#define H 18
#define NS 65536
#define AD 4
#define ITERS 6
#define DELTA 16.0f
#define NWG 1024
#define WGS 128
#define CPB 64        // candidates per block (two lanes share one candidate)
#define NSEG 1024
#define CAPB 64       // per-block segment capacity == CPB => cannot overflow
#define SCAP 1024

__device__ __forceinline__ unsigned encf(float f) {
    unsigned u = __float_as_uint(f);
    return (u & 0x80000000u) ? ~u : (u | 0x80000000u);
}
__device__ __forceinline__ float decf(unsigned u) {
    return __uint_as_float((u & 0x80000000u) ? (u & 0x7FFFFFFFu) : ~u);
}
__device__ __forceinline__ float clamp4f(float x) { return fminf(fmaxf(x, -4.0f), 4.0f); }
// descending u64 order == value desc, then index asc (matches top_k tie-break)
__device__ __forceinline__ unsigned long long packkey(float v, unsigned idx) {
    return ((unsigned long long)encf(v) << 32) | (unsigned long long)(~idx);
}

// One kernel per MPPI iteration. No global atomics; block-owned segments,
// every cross-kernel word re-written each replay (no init needed).
// Candidate n is computed by lane pair (l, l^32): half 0 sums h=0..8,
// half 1 sums h=9..17; one shfl_xor combines. 9 float4 loads per thread,
// hoisted into registers (all in flight, single wait).
__global__ void __launch_bounds__(WGS) k_step(
        const float* __restrict__ pi, const float* __restrict__ noise,
        const float* __restrict__ target, float* __restrict__ meanarr,
        float* __restrict__ bmaxp, float* __restrict__ bmaxc,
        unsigned* __restrict__ cntp, unsigned* __restrict__ cntc,
        float* __restrict__ pvals, unsigned* __restrict__ pidx,
        float* __restrict__ cvals, unsigned* __restrict__ cidx, int iter) {
    __shared__ float tgt[H * AD], mnL[H * AD];
    __shared__ float wmx[2];
    __shared__ unsigned long long skey[SCAP];
    __shared__ float buf[64 * 73];
    __shared__ float w[64];
    __shared__ unsigned s_cnt, s_fcnt;
    __shared__ float s_S;

    const int tid = threadIdx.x;
    const int wg = blockIdx.x;
    const int lane = tid & 63;
    const int wid = tid >> 6;
    const int half = (lane >> 5);            // 0: h 0..8, 1: h 9..17
    const int n = wg * CPB + wid * 32 + (lane & 31);   // candidate index

    if (tid < H * AD) tgt[tid] = target[tid];
    if (tid == 0) { s_cnt = 0u; s_fcnt = 0u; }

    if (iter == 0) {
        if (tid < H * AD) {
            float m0 = pi[(size_t)(tid >> 2) * NS * AD + (tid & 3)];  // pi[:,0,:]
            mnL[tid] = m0;
            meanarr[tid] = m0;   // identical values from all blocks: benign
        }
        __syncthreads();
        // ---- pi candidate values (computed once, pushed to segments)
        const float4* pi4 = (const float4*)pi;
        float4 xs[9];
#pragma unroll
        for (int hh = 0; hh < 9; ++hh)
            xs[hh] = pi4[(size_t)(half * 9 + hh) * NS + n];
        float a2 = 0.f;
#pragma unroll
        for (int hh = 0; hh < 9; ++hh) {
            const int h = half * 9 + hh;
            float c;
            c = xs[hh].x - tgt[h*4+0]; a2 += c*c;
            c = xs[hh].y - tgt[h*4+1]; a2 += c*c;
            c = xs[hh].z - tgt[h*4+2]; a2 += c*c;
            c = xs[hh].w - tgt[h*4+3]; a2 += c*c;
        }
        const float vpi = -(a2 + __shfl_xor(a2, 32));
        float m = vpi;
        for (int off = 16; off; off >>= 1) m = fmaxf(m, __shfl_xor(m, off));
        m = fmaxf(m, __shfl_xor(m, 32));
        if (lane == 0) wmx[wid] = m;
        __syncthreads();
        const float bmax = fmaxf(wmx[0], wmx[1]);
        if (tid == 0) bmaxp[wg] = bmax;
        if (half == 0 && vpi >= bmax - DELTA) {
            unsigned p = atomicAdd(&s_cnt, 1u);
            pvals[wg * CAPB + p] = vpi; pidx[wg * CAPB + p] = (unsigned)n;
        }
        __syncthreads();
        if (tid == 0) { cntp[wg] = s_cnt; s_cnt = 0u; }
        __syncthreads();
    } else {
        // ---- phase B for iter-1 (redundant in every block; identical results)
        if (tid < H * AD) mnL[tid] = meanarr[(size_t)(iter - 1) * H * AD + tid];
        __syncthreads();
        {
            float g = -INFINITY;
            const float* bmc = bmaxc + (size_t)(iter - 1) * NSEG;
            for (int s = tid; s < NSEG; s += WGS) g = fmaxf(g, fmaxf(bmaxp[s], bmc[s]));
            for (int off = 32; off; off >>= 1) g = fmaxf(g, __shfl_xor(g, off));
            if (lane == 0) wmx[wid] = g;
        }
        __syncthreads();
        const float gmax = fmaxf(wmx[0], wmx[1]);
        const float thr = gmax - DELTA;
        // filter: scan all segments, push passers into LDS
        {
            for (int s = tid; s < NSEG; s += WGS) {
                unsigned c = cntp[s];
                for (unsigned k = 0; k < c; ++k) {
                    float val = pvals[s * CAPB + k];
                    if (val >= thr) {
                        unsigned p = atomicAdd(&s_fcnt, 1u);
                        if (p < SCAP) skey[p] = packkey(val, pidx[s * CAPB + k]);
                    }
                }
                c = cntc[(size_t)(iter - 1) * NSEG + s];
                const size_t sb = (size_t)(iter - 1) * NSEG * CAPB + (size_t)s * CAPB;
                for (unsigned k = 0; k < c; ++k) {
                    float val = cvals[sb + k];
                    if (val >= thr) {
                        unsigned p = atomicAdd(&s_fcnt, 1u);
                        if (p < SCAP) skey[p] = packkey(val, cidx[sb + k]);
                    }
                }
            }
        }
        __syncthreads();
        unsigned fc = s_fcnt; if (fc > SCAP) fc = SCAP;
        if (fc > 64u) {   // exact top-64 via bitonic on packed keys
            unsigned P2 = 128; while (P2 < fc) P2 <<= 1;
            for (unsigned k = fc + tid; k < P2; k += WGS) skey[k] = 0ull;
            __syncthreads();
            for (unsigned kk = 2; kk <= P2; kk <<= 1) {
                for (unsigned j = kk >> 1; j; j >>= 1) {
                    for (unsigned x = tid; x < P2; x += WGS) {
                        unsigned l = x ^ j;
                        if (l > x) {
                            unsigned long long k0 = skey[x], k1 = skey[l];
                            bool desc = ((x & kk) == 0);
                            if (desc ? (k0 < k1) : (k0 > k1)) { skey[x] = k1; skey[l] = k0; }
                        }
                    }
                    __syncthreads();
                }
            }
        }
        const int E = (fc < 64u) ? (int)fc : 64;
        if (tid < 64) {
            float we = (tid < E) ? expf(decf((unsigned)(skey[tid] >> 32)) - gmax) : 0.0f;
            w[tid] = we;
            float s = we;
            for (int off = 32; off; off >>= 1) s += __shfl_xor(s, off);
            if (tid == 0) s_S = s;
        }
        __syncthreads();
        const float invS = 1.0f / (s_S * (1.0f + 1e-9f));
        // gather elite actions: thread handles (e, aa) for e and e+32
        {
            const float pscale = (iter - 1 == 0) ? 0.5f : 1.0f;
            const int aa = tid & 3;
#pragma unroll
            for (int rep = 0; rep < 2; ++rep) {
                const int e = (tid >> 2) + rep * 32;
                float av[H];
                unsigned idx = (e < E) ? (unsigned)~(unsigned)(skey[e] & 0xFFFFFFFFull) : 0u;
                if (e < E) {
                    if (idx < NS) {
#pragma unroll
                        for (int h = 0; h < H; ++h)
                            av[h] = pi[(size_t)h * NS * AD + (size_t)idx * AD + aa];
                    } else {
                        const unsigned mm = idx - NS;
                        const float* nzi = noise + (size_t)(iter - 1) * H * NS * AD;
#pragma unroll
                        for (int h = 0; h < H; ++h)
                            av[h] = clamp4f(mnL[h*4+aa] + pscale * nzi[(size_t)h * NS * AD + (size_t)mm * AD + aa]);
                    }
                } else {
#pragma unroll
                    for (int h = 0; h < H; ++h) av[h] = 0.0f;
                }
                const float we = (e < E) ? w[e] : 0.0f;
#pragma unroll
                for (int h = 0; h < H; ++h) buf[e * 73 + h * 4 + aa] = we * av[h];
            }
        }
        __syncthreads();
        if (tid < H * AD) {
            float s = 0.f;
#pragma unroll 8
            for (int e = 0; e < 64; ++e) s += buf[e * 73 + tid];
            float nm = 0.1f * mnL[tid] + 0.9f * (s * invS);
            mnL[tid] = nm;
            meanarr[(size_t)iter * H * AD + tid] = nm;
        }
        __syncthreads();
    }

    // ---- phase A: cem values for this iteration (9 hoisted loads per thread)
    const float scale = (iter == 0) ? 0.5f : 1.0f;
    const float4* nz4 = (const float4*)noise + (size_t)iter * H * NS;
    float4 xs[9];
#pragma unroll
    for (int hh = 0; hh < 9; ++hh)
        xs[hh] = nz4[(size_t)(half * 9 + hh) * NS + n];
    float a2 = 0.f;
#pragma unroll
    for (int hh = 0; hh < 9; ++hh) {
        const int h = half * 9 + hh;
        float c;
        c = clamp4f(mnL[h*4+0] + scale * xs[hh].x) - tgt[h*4+0]; a2 += c*c;
        c = clamp4f(mnL[h*4+1] + scale * xs[hh].y) - tgt[h*4+1]; a2 += c*c;
        c = clamp4f(mnL[h*4+2] + scale * xs[hh].z) - tgt[h*4+2]; a2 += c*c;
        c = clamp4f(mnL[h*4+3] + scale * xs[hh].w) - tgt[h*4+3]; a2 += c*c;
    }
    const float vc = -(a2 + __shfl_xor(a2, 32));
    float m2 = vc;
    for (int off = 16; off; off >>= 1) m2 = fmaxf(m2, __shfl_xor(m2, off));
    m2 = fmaxf(m2, __shfl_xor(m2, 32));
    if (lane == 0) wmx[wid] = m2;
    __syncthreads();
    const float bmax2 = fmaxf(wmx[0], wmx[1]);
    if (tid == 0) bmaxc[(size_t)iter * NSEG + wg] = bmax2;
    if (half == 0 && vc >= bmax2 - DELTA) {
        unsigned p = atomicAdd(&s_cnt, 1u);
        size_t slot = (size_t)iter * NSEG * CAPB + (size_t)wg * CAPB + p;
        cvals[slot] = vc; cidx[slot] = (unsigned)(NS + n);
    }
    __syncthreads();
    if (tid == 0) cntc[(size_t)iter * NSEG + wg] = s_cnt;
}

// ---- final: one block, exact argmax over (pi-segments ∪ cem5-segments)
__global__ void __launch_bounds__(WGS) k_fin(
        const float* __restrict__ pi, const float* __restrict__ noise,
        const float* __restrict__ meanarr,
        const unsigned* __restrict__ cntp, const unsigned* __restrict__ cntc,
        const float* __restrict__ pvals, const unsigned* __restrict__ pidx,
        const float* __restrict__ cvals, const unsigned* __restrict__ cidx,
        float* __restrict__ out) {
    __shared__ float mnL[H * AD];
    __shared__ unsigned long long wk[2];
    const int tid = threadIdx.x, lane = tid & 63, wid = tid >> 6;
    if (tid < H * AD) mnL[tid] = meanarr[(size_t)5 * H * AD + tid];
    unsigned long long bk = 0ull;
    for (int s = tid; s < NSEG; s += WGS) {
        unsigned c = cntp[s];
        for (unsigned k = 0; k < c; ++k) {
            unsigned long long key = packkey(pvals[s * CAPB + k], pidx[s * CAPB + k]);
            if (key > bk) bk = key;
        }
        c = cntc[(size_t)5 * NSEG + s];
        const size_t sb = (size_t)5 * NSEG * CAPB + (size_t)s * CAPB;
        for (unsigned k = 0; k < c; ++k) {
            unsigned long long key = packkey(cvals[sb + k], cidx[sb + k]);
            if (key > bk) bk = key;
        }
    }
    for (int off = 32; off; off >>= 1) {
        unsigned long long ok = __shfl_xor(bk, off);
        if (ok > bk) bk = ok;
    }
    if (lane == 0) wk[wid] = bk;
    __syncthreads();
    if (tid == 0) wk[0] = (wk[1] > wk[0]) ? wk[1] : wk[0];
    __syncthreads();
    const unsigned idx = (unsigned)~(unsigned)(wk[0] & 0xFFFFFFFFull);
    if (tid < H * AD) {
        const int h = tid >> 2, aa = tid & 3;
        float o;
        if (idx < NS) o = pi[(size_t)h * NS * AD + (size_t)idx * AD + aa];
        else o = clamp4f(mnL[tid] + 1.0f * noise[(size_t)5 * H * NS * AD + (size_t)h * NS * AD + (size_t)(idx - NS) * AD + aa]);
        out[tid] = o;
    }
}

extern "C" void kernel_launch(void* const* d_in, const int* in_sizes, int n_in,
                              void* d_out, int out_size, void* d_ws, size_t ws_size,
                              hipStream_t stream) {
    const float* pi     = (const float*)d_in[0];
    const float* noise  = (const float*)d_in[1];
    const float* target = (const float*)d_in[2];
    float* out = (float*)d_out;

    float* ws = (float*)d_ws;
    float* meanarr  = ws;                                     // 6*72 (pad 512)
    float* bmaxp    = meanarr + 512;                          // NSEG
    float* bmaxc    = bmaxp + NSEG;                           // 6*NSEG
    unsigned* cntp  = (unsigned*)(bmaxc + ITERS * NSEG);      // NSEG
    unsigned* cntc  = cntp + NSEG;                            // 6*NSEG
    float* pvals    = (float*)(cntc + ITERS * NSEG);          // NSEG*CAPB
    unsigned* pidx  = (unsigned*)(pvals + NSEG * CAPB);       // NSEG*CAPB
    float* cvals    = (float*)(pidx + NSEG * CAPB);           // 6*NSEG*CAPB
    unsigned* cidx  = (unsigned*)(cvals + (size_t)ITERS * NSEG * CAPB);

    for (int i = 0; i < ITERS; ++i)
        k_step<<<NWG, WGS, 0, stream>>>(pi, noise, target, meanarr, bmaxp, bmaxc,
                                        cntp, cntc, pvals, pidx, cvals, cidx, i);
    k_fin<<<1, WGS, 0, stream>>>(pi, noise, meanarr, cntp, cntc,
                                 pvals, pidx, cvals, cidx, out);
}

// Round 11
// 213.730 us; speedup vs baseline: 2.8061x; 2.8061x over previous
//
#include <hip/hip_runtime.h>
#include <math.h>

#define H 18
#define NS 65536
#define AD 4
#define ITERS 6
#define DELTA 16.0f
#define NWG 256
#define WGS 256
#define CAPB 256
#define SCAP 2048
#define PFCAP 4096

__device__ __forceinline__ unsigned encf(float f) {
    unsigned u = __float_as_uint(f);
    return (u & 0x80000000u) ? ~u : (u | 0x80000000u);
}
__device__ __forceinline__ float decf(unsigned u) {
    return __uint_as_float((u & 0x80000000u) ? (u & 0x7FFFFFFFu) : ~u);
}
__device__ __forceinline__ float clamp4f(float x) { return fminf(fmaxf(x, -4.0f), 4.0f); }
// descending u64 order == value desc, then index asc (matches top_k tie-break)
__device__ __forceinline__ unsigned long long packkey(float v, unsigned idx) {
    return ((unsigned long long)encf(v) << 32) | (unsigned long long)(~idx);
}

// Wide evaluation kernel: 1 thread = 1 candidate; 18 float4 loads hoisted into
// registers (all in flight, single wait). mode 0: pi candidates (also seeds
// meanarr[0]); mode 1: cem candidates. Pushes to block-owned segments with
// threshold max(blockmax, watermark) - DELTA. No global atomics.
__global__ void __launch_bounds__(WGS, 1) k_value(
        const float4* __restrict__ src4, const float* __restrict__ pi,
        const float* __restrict__ target, float* __restrict__ meanarr,
        const float* __restrict__ pimaxp,
        float* __restrict__ bmax_o, unsigned* __restrict__ cnt_o,
        float* __restrict__ vals_o, unsigned* __restrict__ idx_o,
        int mode, float scale, int mean_off, int use_wm, unsigned idx_base) {
    __shared__ float tgt[H * AD], mnL[H * AD];
    __shared__ float wmx[4];
    __shared__ unsigned s_cnt;
    const int tid = threadIdx.x, wg = blockIdx.x;
    const int lane = tid & 63, wid = tid >> 6;
    const int n = wg * WGS + tid;

    // issue all 18 independent loads first
    float4 xs[18];
#pragma unroll
    for (int h = 0; h < H; ++h) xs[h] = src4[(size_t)h * NS + n];

    if (tid < H * AD) tgt[tid] = target[tid];
    if (mode == 0) {
        if (tid < H * AD) {
            float m0 = pi[(size_t)(tid >> 2) * NS * AD + (tid & 3)];  // pi[:,0,:]
            mnL[tid] = m0;
            meanarr[tid] = m0;   // identical from all blocks: benign
        }
    } else {
        if (tid < H * AD) mnL[tid] = meanarr[mean_off + tid];
    }
    if (tid == 0) s_cnt = 0u;
    __syncthreads();

    float a2 = 0.f;
    if (mode == 0) {
#pragma unroll
        for (int h = 0; h < H; ++h) {
            float c;
            c = xs[h].x - tgt[h*4+0]; a2 += c*c;
            c = xs[h].y - tgt[h*4+1]; a2 += c*c;
            c = xs[h].z - tgt[h*4+2]; a2 += c*c;
            c = xs[h].w - tgt[h*4+3]; a2 += c*c;
        }
    } else {
#pragma unroll
        for (int h = 0; h < H; ++h) {
            float c;
            c = clamp4f(mnL[h*4+0] + scale * xs[h].x) - tgt[h*4+0]; a2 += c*c;
            c = clamp4f(mnL[h*4+1] + scale * xs[h].y) - tgt[h*4+1]; a2 += c*c;
            c = clamp4f(mnL[h*4+2] + scale * xs[h].z) - tgt[h*4+2]; a2 += c*c;
            c = clamp4f(mnL[h*4+3] + scale * xs[h].w) - tgt[h*4+3]; a2 += c*c;
        }
    }
    const float v = -a2;
    float m = v;
    for (int off = 32; off; off >>= 1) m = fmaxf(m, __shfl_xor(m, off));
    if (lane == 0) wmx[wid] = m;
    __syncthreads();
    const float bmax = fmaxf(fmaxf(wmx[0], wmx[1]), fmaxf(wmx[2], wmx[3]));
    if (tid == 0) bmax_o[wg] = bmax;
    const float wm = use_wm ? *pimaxp : -INFINITY;
    const float thr = fmaxf(bmax, wm) - DELTA;
    if (v >= thr) {
        unsigned p = atomicAdd(&s_cnt, 1u);
        vals_o[wg * CAPB + p] = v;
        idx_o[wg * CAPB + p] = idx_base + (unsigned)n;
    }
    __syncthreads();
    if (tid == 0) cnt_o[wg] = s_cnt;
}

// Single-block reduction: exact gmax, filter (>= gmax-16), exact top-64,
// softmax, elite gather, mean update. is_first: also computes/stores pimax
// and compacts pi survivors (>= pimax-16) into pfk. is_last: argmax + output.
__global__ void __launch_bounds__(1024) k_reduce(
        const float* __restrict__ pi, const float* __restrict__ noise_i,
        float* __restrict__ meanarr, float* __restrict__ pimaxp,
        const float* __restrict__ bmaxp, const unsigned* __restrict__ cntp,
        const float* __restrict__ pvals, const unsigned* __restrict__ pidx,
        const float* __restrict__ bmaxc_i, const unsigned* __restrict__ cntc_i,
        const float* __restrict__ cvals_i, const unsigned* __restrict__ cidx_i,
        unsigned long long* __restrict__ pfk, unsigned* __restrict__ pfcnt,
        float* __restrict__ out, int iter, int is_first, int is_last, float scale_i) {
    __shared__ unsigned long long skey[SCAP];
    __shared__ unsigned long long wk[16];
    __shared__ float mnL[H * AD], w[64], redf[16];
    __shared__ float buf[64 * 73];
    __shared__ unsigned s_fcnt, s_pf;
    __shared__ float s_gmax, s_pimax, s_S;
    const int tid = threadIdx.x, lane = tid & 63, wid = tid >> 6;

    if (tid < H * AD) mnL[tid] = meanarr[iter * H * AD + tid];
    if (tid == 0) { s_fcnt = 0u; s_pf = 0u; }

    // ---- pimax
    if (is_first) {
        float g = (tid < NWG) ? bmaxp[tid] : -INFINITY;
        for (int off = 32; off; off >>= 1) g = fmaxf(g, __shfl_xor(g, off));
        if (lane == 0) redf[wid] = g;
        __syncthreads();
        if (tid == 0) {
            float x = redf[0];
            for (int q = 1; q < 16; ++q) x = fmaxf(x, redf[q]);
            s_pimax = x; *pimaxp = x;
        }
    } else {
        if (tid == 0) s_pimax = *pimaxp;
    }
    __syncthreads();
    // ---- gmax = max(pimax, cemmax_i)
    {
        float g = (tid < NWG) ? bmaxc_i[tid] : -INFINITY;
        for (int off = 32; off; off >>= 1) g = fmaxf(g, __shfl_xor(g, off));
        if (lane == 0) redf[wid] = g;
        __syncthreads();
        if (tid == 0) {
            float x = redf[0];
            for (int q = 1; q < 16; ++q) x = fmaxf(x, redf[q]);
            s_gmax = fmaxf(s_pimax, x);
        }
    }
    __syncthreads();
    const float gmax = s_gmax, pimax = s_pimax;
    const float thr = gmax - DELTA;

    // ---- filter pi side
    if (is_first) {
        const float pthr = pimax - DELTA;
        if (tid < NWG) {
            unsigned c = cntp[tid];
            for (unsigned k = 0; k < c; ++k) {
                float val = pvals[tid * CAPB + k];
                unsigned long long key = packkey(val, pidx[tid * CAPB + k]);
                if (val >= pthr) {
                    unsigned q = atomicAdd(&s_pf, 1u);
                    if (q < PFCAP) pfk[q] = key;
                }
                if (val >= thr) {
                    unsigned p = atomicAdd(&s_fcnt, 1u);
                    if (p < SCAP) skey[p] = key;
                }
            }
        }
    } else {
        unsigned pc = *pfcnt; if (pc > PFCAP) pc = PFCAP;
        for (unsigned k = tid; k < pc; k += 1024) {
            unsigned long long key = pfk[k];
            float val = decf((unsigned)(key >> 32));
            if (val >= thr) {
                unsigned p = atomicAdd(&s_fcnt, 1u);
                if (p < SCAP) skey[p] = key;
            }
        }
    }
    // ---- filter cem side
    if (tid < NWG) {
        unsigned c = cntc_i[tid];
        for (unsigned k = 0; k < c; ++k) {
            float val = cvals_i[tid * CAPB + k];
            if (val >= thr) {
                unsigned p = atomicAdd(&s_fcnt, 1u);
                if (p < SCAP) skey[p] = packkey(val, cidx_i[tid * CAPB + k]);
            }
        }
    }
    __syncthreads();
    if (is_first && tid == 0) *pfcnt = (s_pf > PFCAP) ? PFCAP : s_pf;
    unsigned fc = s_fcnt; if (fc > SCAP) fc = SCAP;

    if (is_last) {
        // ---- exact argmax over the filtered set (global max is in it)
        unsigned long long bk = 0ull;
        for (unsigned k = tid; k < fc; k += 1024) if (skey[k] > bk) bk = skey[k];
        for (int off = 32; off; off >>= 1) {
            unsigned long long ok = __shfl_xor(bk, off);
            if (ok > bk) bk = ok;
        }
        if (lane == 0) wk[wid] = bk;
        __syncthreads();
        if (tid == 0) {
            unsigned long long b0 = wk[0];
            for (int q = 1; q < 16; ++q) if (wk[q] > b0) b0 = wk[q];
            wk[0] = b0;
        }
        __syncthreads();
        const unsigned idx = (unsigned)~(unsigned)(wk[0] & 0xFFFFFFFFull);
        if (tid < H * AD) {
            const int h = tid >> 2, aa = tid & 3;
            float o;
            if (idx < NS) o = pi[(size_t)h * NS * AD + (size_t)idx * AD + aa];
            else o = clamp4f(mnL[tid] + scale_i * noise_i[(size_t)h * NS * AD + (size_t)(idx - NS) * AD + aa]);
            out[tid] = o;
        }
        return;
    }

    if (fc > 64u) {   // exact top-64 via bitonic on packed keys
        unsigned P2 = 128; while (P2 < fc) P2 <<= 1;
        for (unsigned k = fc + tid; k < P2; k += 1024) skey[k] = 0ull;
        __syncthreads();
        for (unsigned kk = 2; kk <= P2; kk <<= 1) {
            for (unsigned j = kk >> 1; j; j >>= 1) {
                for (unsigned x = tid; x < P2; x += 1024) {
                    unsigned l = x ^ j;
                    if (l > x) {
                        unsigned long long k0 = skey[x], k1 = skey[l];
                        bool desc = ((x & kk) == 0);
                        if (desc ? (k0 < k1) : (k0 > k1)) { skey[x] = k1; skey[l] = k0; }
                    }
                }
                __syncthreads();
            }
        }
    } else {
        __syncthreads();
    }
    const int E = (fc < 64u) ? (int)fc : 64;
    if (tid < 64) {
        float we = (tid < E) ? expf(decf((unsigned)(skey[tid] >> 32)) - gmax) : 0.0f;
        w[tid] = we;
        float s = we;
        for (int off = 32; off; off >>= 1) s += __shfl_xor(s, off);
        if (tid == 0) s_S = s;
    }
    __syncthreads();
    const float invS = 1.0f / (s_S * (1.0f + 1e-9f));
    // ---- elite gather: 4608 independent loads spread over 1024 threads
    for (int el = tid; el < 64 * H * AD; el += 1024) {
        const int e = el / (H * AD), j = el - e * (H * AD);
        const int h = j >> 2, aa = j & 3;
        float av = 0.f;
        if (e < E) {
            const unsigned idx = (unsigned)~(unsigned)(skey[e] & 0xFFFFFFFFull);
            if (idx < NS) av = pi[(size_t)h * NS * AD + (size_t)idx * AD + aa];
            else av = clamp4f(mnL[j] + scale_i * noise_i[(size_t)h * NS * AD + (size_t)(idx - NS) * AD + aa]);
            av *= w[e];
        }
        buf[e * 73 + j] = av;
    }
    __syncthreads();
    if (tid < H * AD) {
        float s = 0.f;
#pragma unroll 8
        for (int e = 0; e < 64; ++e) s += buf[e * 73 + tid];
        meanarr[(iter + 1) * H * AD + tid] = 0.1f * mnL[tid] + 0.9f * (s * invS);
    }
}

extern "C" void kernel_launch(void* const* d_in, const int* in_sizes, int n_in,
                              void* d_out, int out_size, void* d_ws, size_t ws_size,
                              hipStream_t stream) {
    const float* pi     = (const float*)d_in[0];
    const float* noise  = (const float*)d_in[1];
    const float* target = (const float*)d_in[2];
    float* out = (float*)d_out;

    float* ws = (float*)d_ws;
    float* meanarr  = ws;                                     // 8*72 (pad 1024)
    float* pimaxp   = meanarr + 1024;                         // 1
    unsigned* pfcnt = (unsigned*)(pimaxp + 1);                // 1 (+pad to 8)
    float* bmaxp    = (float*)(pfcnt + 7);                    // NWG
    float* bmaxc    = bmaxp + NWG;                            // 6*NWG
    unsigned* cntp  = (unsigned*)(bmaxc + ITERS * NWG);       // NWG
    unsigned* cntc  = cntp + NWG;                             // 6*NWG
    float* pvals    = (float*)(cntc + ITERS * NWG);           // NWG*CAPB
    unsigned* pidx  = (unsigned*)(pvals + NWG * CAPB);        // NWG*CAPB
    float* cvals    = (float*)(pidx + NWG * CAPB);            // 6*NWG*CAPB
    unsigned* cidx  = (unsigned*)(cvals + (size_t)ITERS * NWG * CAPB);
    unsigned long long* pfk = (unsigned long long*)(((size_t)(cidx + (size_t)ITERS * NWG * CAPB) + 15) & ~(size_t)15);

    // pi evaluation (also seeds meanarr[0] = pi[:,0,:])
    k_value<<<NWG, WGS, 0, stream>>>((const float4*)pi, pi, target, meanarr, pimaxp,
                                     bmaxp, cntp, pvals, pidx, 0, 0.f, 0, 0, 0u);
    for (int i = 0; i < ITERS; ++i) {
        const float scale = (i == 0) ? 0.5f : 1.0f;
        const float* nzi = noise + (size_t)i * H * NS * AD;
        k_value<<<NWG, WGS, 0, stream>>>((const float4*)nzi, pi, target, meanarr, pimaxp,
                                         bmaxc + i * NWG, cntc + i * NWG,
                                         cvals + (size_t)i * NWG * CAPB,
                                         cidx + (size_t)i * NWG * CAPB,
                                         1, scale, i * H * AD, (i >= 1) ? 1 : 0, (unsigned)NS);
        k_reduce<<<1, 1024, 0, stream>>>(pi, nzi, meanarr, pimaxp,
                                         bmaxp, cntp, pvals, pidx,
                                         bmaxc + i * NWG, cntc + i * NWG,
                                         cvals + (size_t)i * NWG * CAPB,
                                         cidx + (size_t)i * NWG * CAPB,
                                         pfk, pfcnt, out, i,
                                         (i == 0) ? 1 : 0, (i == ITERS - 1) ? 1 : 0, scale);
    }
}

// Round 12
// 194.832 us; speedup vs baseline: 3.0783x; 1.0970x over previous
//
#include <hip/hip_runtime.h>
#include <math.h>

#define H 18
#define NS 65536
#define AD 4
#define ITERS 6
#define DELTA 16.0f
#define VWG 512
#define VTH 256
#define RTH 1024
#define SCAP 2048
#define PFCAP 4096

__device__ __forceinline__ unsigned encf(float f) {
    unsigned u = __float_as_uint(f);
    return (u & 0x80000000u) ? ~u : (u | 0x80000000u);
}
__device__ __forceinline__ float decf(unsigned u) {
    return __uint_as_float((u & 0x80000000u) ? (u & 0x7FFFFFFFu) : ~u);
}
__device__ __forceinline__ float clamp4f(float x) { return fminf(fmaxf(x, -4.0f), 4.0f); }
// descending u64 order == value desc, then index asc (matches top_k tie-break)
__device__ __forceinline__ unsigned long long packkey(float v, unsigned idx) {
    return ((unsigned long long)encf(v) << 32) | (unsigned long long)(~idx);
}

// Dense evaluation: candidate n handled by lane pair (l, l^32) of one wave
// (half 0 sums h=0..8, half 1 h=9..17; one shfl_xor combines). 9 (or 18 on
// iter 0, which also evaluates pi) float4 loads hoisted into registers.
// Outputs: dense v arrays + per-block maxima. No atomics, no pushes.
__global__ void __launch_bounds__(VTH, 2) k_value(
        const float4* __restrict__ nz4, const float4* __restrict__ pi4,
        const float* __restrict__ target, float* __restrict__ meanarr,
        float* __restrict__ v_cem, float* __restrict__ bmax_cem,
        float* __restrict__ v_pi, float* __restrict__ bmax_pi,
        int mean_off, float scale, int do_pi) {
    __shared__ float tgt[H * AD], mnL[H * AD];
    __shared__ float wmx[4], wmp[4];
    const int tid = threadIdx.x, wg = blockIdx.x;
    const int lane = tid & 63, wid = tid >> 6;
    const int half = lane >> 5;
    const int n = wg * 128 + wid * 32 + (lane & 31);

    float4 xs[9];
#pragma unroll
    for (int hh = 0; hh < 9; ++hh)
        xs[hh] = nz4[(size_t)(half * 9 + hh) * NS + n];
    float4 ps[9];
    if (do_pi) {
#pragma unroll
        for (int hh = 0; hh < 9; ++hh)
            ps[hh] = pi4[(size_t)(half * 9 + hh) * NS + n];
    }

    if (tid < H * AD) tgt[tid] = target[tid];
    if (do_pi) {
        if (tid < H * AD) {
            float m0 = ((const float*)pi4)[(size_t)(tid >> 2) * NS * AD + (tid & 3)];
            mnL[tid] = m0;
            meanarr[tid] = m0;   // identical from all blocks: benign
        }
    } else {
        if (tid < H * AD) mnL[tid] = meanarr[mean_off + tid];
    }
    __syncthreads();

    float a2 = 0.f;
#pragma unroll
    for (int hh = 0; hh < 9; ++hh) {
        const int h = half * 9 + hh;
        float c;
        c = clamp4f(mnL[h*4+0] + scale * xs[hh].x) - tgt[h*4+0]; a2 += c*c;
        c = clamp4f(mnL[h*4+1] + scale * xs[hh].y) - tgt[h*4+1]; a2 += c*c;
        c = clamp4f(mnL[h*4+2] + scale * xs[hh].z) - tgt[h*4+2]; a2 += c*c;
        c = clamp4f(mnL[h*4+3] + scale * xs[hh].w) - tgt[h*4+3]; a2 += c*c;
    }
    const float vc = -(a2 + __shfl_xor(a2, 32));
    if (half == 0) v_cem[n] = vc;
    float m = vc;
    for (int off = 16; off; off >>= 1) m = fmaxf(m, __shfl_xor(m, off));
    if (lane == 0) wmx[wid] = m;

    if (do_pi) {
        float p2 = 0.f;
#pragma unroll
        for (int hh = 0; hh < 9; ++hh) {
            const int h = half * 9 + hh;
            float c;
            c = ps[hh].x - tgt[h*4+0]; p2 += c*c;
            c = ps[hh].y - tgt[h*4+1]; p2 += c*c;
            c = ps[hh].z - tgt[h*4+2]; p2 += c*c;
            c = ps[hh].w - tgt[h*4+3]; p2 += c*c;
        }
        const float vp = -(p2 + __shfl_xor(p2, 32));
        if (half == 0) v_pi[n] = vp;
        float mp = vp;
        for (int off = 16; off; off >>= 1) mp = fmaxf(mp, __shfl_xor(mp, off));
        if (lane == 0) wmp[wid] = mp;
    }
    __syncthreads();
    if (tid == 0) {
        bmax_cem[wg] = fmaxf(fmaxf(wmx[0], wmx[1]), fmaxf(wmx[2], wmx[3]));
        if (do_pi) bmax_pi[wg] = fmaxf(fmaxf(wmp[0], wmp[1]), fmaxf(wmp[2], wmp[3]));
    }
}

// Single-block reduction: exact gmax, parallel dense scan with exact threshold
// gmax-DELTA, bitonic top-64, softmax, gather, momentum mean update.
// is_first: computes pimax, compacts pi survivors (>= pimax-16) into pfk.
// is_last: writes output = actions of the exact argmax.
__global__ void __launch_bounds__(RTH) k_reduce(
        const float* __restrict__ pi, const float* __restrict__ noise_i,
        float* __restrict__ meanarr, float* __restrict__ pimaxp,
        const float* __restrict__ bmax_pi, const float* __restrict__ v_pi,
        const float* __restrict__ bmax_cem, const float* __restrict__ v_cem,
        unsigned long long* __restrict__ pfk, unsigned* __restrict__ pfcnt,
        float* __restrict__ out, int iter, int is_first, int is_last, float scale_i) {
    __shared__ unsigned long long skey[SCAP];
    __shared__ float mnL[H * AD], w[64], redf[16];
    __shared__ float buf[64 * 73];
    __shared__ unsigned s_fcnt, s_pf;
    __shared__ float s_S, s_gmax, s_pimax;
    const int tid = threadIdx.x, lane = tid & 63, wid = tid >> 6;

    if (tid < H * AD) mnL[tid] = meanarr[iter * H * AD + tid];
    if (tid == 0) { s_fcnt = 0u; s_pf = 0u; }

    // ---- pimax
    if (is_first) {
        float g = (tid < VWG) ? bmax_pi[tid] : -INFINITY;
        for (int off = 32; off; off >>= 1) g = fmaxf(g, __shfl_xor(g, off));
        if (lane == 0) redf[wid] = g;
        __syncthreads();
        if (tid == 0) {
            float x = redf[0];
            for (int q = 1; q < 16; ++q) x = fmaxf(x, redf[q]);
            s_pimax = x; *pimaxp = x;
        }
        __syncthreads();
    } else {
        if (tid == 0) s_pimax = *pimaxp;
        __syncthreads();
    }
    // ---- gmax = max(pimax, cem max)
    {
        float g = (tid < VWG) ? bmax_cem[tid] : -INFINITY;
        for (int off = 32; off; off >>= 1) g = fmaxf(g, __shfl_xor(g, off));
        if (lane == 0) redf[wid] = g;
        __syncthreads();
        if (tid == 0) {
            float x = redf[0];
            for (int q = 1; q < 16; ++q) x = fmaxf(x, redf[q]);
            s_gmax = fmaxf(s_pimax, x);
        }
        __syncthreads();
    }
    const float gmax = s_gmax;
    const float thr = gmax - DELTA;

    // ---- pi survivors
    if (is_first) {
        const float pthr = s_pimax - DELTA;   // <= thr side: pthr <= gmax-16? no: pthr<=thr since pimax<=gmax
        const float4* vp4 = (const float4*)v_pi;
        for (int k = tid; k < NS / 4; k += RTH) {
            float4 x = vp4[k];
            float vv[4] = {x.x, x.y, x.z, x.w};
#pragma unroll
            for (int c2 = 0; c2 < 4; ++c2) {
                float val = vv[c2];
                if (val >= pthr) {
                    unsigned long long key = packkey(val, 4u * k + c2);
                    unsigned q = atomicAdd(&s_pf, 1u);
                    if (q < PFCAP) pfk[q] = key;
                    if (val >= thr) {
                        unsigned p = atomicAdd(&s_fcnt, 1u);
                        if (p < SCAP) skey[p] = key;
                    }
                }
            }
        }
    } else {
        unsigned pc = *pfcnt; if (pc > PFCAP) pc = PFCAP;
        for (unsigned k = tid; k < pc; k += RTH) {
            unsigned long long key = pfk[k];
            if (decf((unsigned)(key >> 32)) >= thr) {
                unsigned p = atomicAdd(&s_fcnt, 1u);
                if (p < SCAP) skey[p] = key;
            }
        }
    }
    // ---- cem survivors
    {
        const float4* vc4 = (const float4*)v_cem;
        for (int k = tid; k < NS / 4; k += RTH) {
            float4 x = vc4[k];
            float vv[4] = {x.x, x.y, x.z, x.w};
#pragma unroll
            for (int c2 = 0; c2 < 4; ++c2) {
                float val = vv[c2];
                if (val >= thr) {
                    unsigned p = atomicAdd(&s_fcnt, 1u);
                    if (p < SCAP) skey[p] = packkey(val, NS + 4u * k + c2);
                }
            }
        }
    }
    __syncthreads();
    if (is_first && tid == 0) *pfcnt = (s_pf > PFCAP) ? PFCAP : s_pf;
    unsigned fc = s_fcnt; if (fc > SCAP) fc = SCAP;

    // ---- bitonic sort (always: deterministic order + skey[0] = exact argmax)
    unsigned P2 = 128; while (P2 < fc) P2 <<= 1;
    for (unsigned k = fc + tid; k < P2; k += RTH) skey[k] = 0ull;
    __syncthreads();
    for (unsigned kk = 2; kk <= P2; kk <<= 1) {
        for (unsigned j = kk >> 1; j; j >>= 1) {
            for (unsigned x = tid; x < P2; x += RTH) {
                unsigned l = x ^ j;
                if (l > x) {
                    unsigned long long k0 = skey[x], k1 = skey[l];
                    bool desc = ((x & kk) == 0);
                    if (desc ? (k0 < k1) : (k0 > k1)) { skey[x] = k1; skey[l] = k0; }
                }
            }
            __syncthreads();
        }
    }

    if (is_last) {
        const unsigned idx = (unsigned)~(unsigned)(skey[0] & 0xFFFFFFFFull);
        if (tid < H * AD) {
            const int h = tid >> 2, aa = tid & 3;
            float o;
            if (idx < NS) o = pi[(size_t)h * NS * AD + (size_t)idx * AD + aa];
            else o = clamp4f(mnL[tid] + scale_i * noise_i[(size_t)h * NS * AD + (size_t)(idx - NS) * AD + aa]);
            out[tid] = o;
        }
        return;
    }

    const int E = (fc < 64u) ? (int)fc : 64;
    if (tid < 64) {
        float we = (tid < E) ? expf(decf((unsigned)(skey[tid] >> 32)) - gmax) : 0.0f;
        w[tid] = we;
        float s = we;
        for (int off = 32; off; off >>= 1) s += __shfl_xor(s, off);
        if (tid == 0) s_S = s;
    }
    __syncthreads();
    const float invS = 1.0f / (s_S * (1.0f + 1e-9f));
    // ---- elite gather: 4608 independent loads across 1024 threads
    for (int el = tid; el < 64 * H * AD; el += RTH) {
        const int e = el / (H * AD), j = el - e * (H * AD);
        const int h = j >> 2, aa = j & 3;
        float av = 0.f;
        if (e < E) {
            const unsigned idx = (unsigned)~(unsigned)(skey[e] & 0xFFFFFFFFull);
            if (idx < NS) av = pi[(size_t)h * NS * AD + (size_t)idx * AD + aa];
            else av = clamp4f(mnL[j] + scale_i * noise_i[(size_t)h * NS * AD + (size_t)(idx - NS) * AD + aa]);
            av *= w[e];
        }
        buf[e * 73 + j] = av;
    }
    __syncthreads();
    if (tid < H * AD) {
        float s = 0.f;
#pragma unroll 8
        for (int e = 0; e < 64; ++e) s += buf[e * 73 + tid];
        meanarr[(iter + 1) * H * AD + tid] = 0.1f * mnL[tid] + 0.9f * (s * invS);
    }
}

extern "C" void kernel_launch(void* const* d_in, const int* in_sizes, int n_in,
                              void* d_out, int out_size, void* d_ws, size_t ws_size,
                              hipStream_t stream) {
    const float* pi     = (const float*)d_in[0];
    const float* noise  = (const float*)d_in[1];
    const float* target = (const float*)d_in[2];
    float* out = (float*)d_out;

    float* ws = (float*)d_ws;
    float* meanarr  = ws;                                     // 8*72 (pad 1024)
    float* pimaxp   = meanarr + 1024;                         // 1
    unsigned* pfcnt = (unsigned*)(pimaxp + 1);                // 1 (+pad to 8)
    float* bmax_pi  = (float*)(pfcnt + 7);                    // VWG
    float* bmax_cem = bmax_pi + VWG;                          // VWG
    float* v_pi     = bmax_cem + VWG;                         // NS
    float* v_cem    = v_pi + NS;                              // NS
    unsigned long long* pfk =
        (unsigned long long*)(((size_t)(v_cem + NS) + 15) & ~(size_t)15);  // PFCAP

    for (int i = 0; i < ITERS; ++i) {
        const float scale = (i == 0) ? 0.5f : 1.0f;
        const float* nzi = noise + (size_t)i * H * NS * AD;
        k_value<<<VWG, VTH, 0, stream>>>((const float4*)nzi, (const float4*)pi,
                                         target, meanarr, v_cem, bmax_cem,
                                         v_pi, bmax_pi, i * H * AD, scale,
                                         (i == 0) ? 1 : 0);
        k_reduce<<<1, RTH, 0, stream>>>(pi, nzi, meanarr, pimaxp,
                                        bmax_pi, v_pi, bmax_cem, v_cem,
                                        pfk, pfcnt, out, i,
                                        (i == 0) ? 1 : 0, (i == ITERS - 1) ? 1 : 0, scale);
    }
}